// Round 8
// baseline (94.750 us; speedup 1.0000x reference)
//
#include <hip/hip_runtime.h>
#include <hip/hip_bf16.h>
#include <stdint.h>

typedef __bf16 bf16_t;
typedef bf16_t bf16x8 __attribute__((ext_vector_type(8)));
typedef float f32x4 __attribute__((ext_vector_type(4)));

#define DEVI static __device__ __forceinline__

constexpr int NB = 32, CIN = 256, COUT = 256, KNUM = 6, ET = 3, TDIM = 64, VV = 25;
constexpr int KD   = KNUM * CIN;       // 1536 contraction dim (k,ci)
constexpr long OUT0 = (long)NB * COUT * TDIM * VV;  // 13107200 (x_sum elems)
constexpr int ACNT = ET * VV * VV;     // 1875 (A copy)

// wp3: W in fragment-order. 24 steps x 2048 chunks x 16B = 768 KB. (R7 layout)
constexpr int NSTEP = 24;              // 4 cb x 6 k
constexpr int WP3_CHUNKS = NSTEP * 2048;
constexpr size_t WP3_BYTES  = (size_t)WP3_CHUNKS * 16;      // 768 KB
constexpr size_t BIAS_OFF   = WP3_BYTES;
constexpr size_t BIAS_BYTES = (size_t)NB * VV * COUT * 4;   // bias [n][w][c] f32
constexpr size_t WS_NEED    = BIAS_OFF + BIAS_BYTES;

DEVI unsigned packbf(float lo, float hi) {
  unsigned short a = __builtin_bit_cast(unsigned short, (bf16_t)lo);
  unsigned short b = __builtin_bit_cast(unsigned short, (bf16_t)hi);
  return ((unsigned)b << 16) | (unsigned)a;
}

DEVI bf16x8 pack8(f32x4 a, f32x4 b) {
  union { unsigned u[4]; bf16x8 v; } u;
  u.u[0] = packbf(a[0], a[1]); u.u[1] = packbf(a[2], a[3]);
  u.u[2] = packbf(b[0], b[1]); u.u[3] = packbf(b[2], b[3]);
  return u.v;
}

// ---------------- prep: wp3 fragment-layout + bias table + A copy ----------
__global__ __launch_bounds__(256) void prep_kernel(
    const float* __restrict__ A, const float* __restrict__ Bm,
    const float* __restrict__ lam_p, const float* __restrict__ W,
    const float* __restrict__ bvec, bf16_t* __restrict__ wp3,
    float* __restrict__ biasmat, float* __restrict__ outA)
{
  int idx = blockIdx.x * 256 + threadIdx.x;
  constexpr int S1 = WP3_CHUNKS;            // 49152 (one 16B chunk per thread)
  constexpr int S2 = S1 + NB * VV * COUT;   // +204800
  constexpr int S3 = S2 + ACNT;
  if (idx < S1) {
    int s  = idx >> 11;
    int r  = idx & 2047;
    int mi = r >> 7;
    int kk = (r >> 6) & 1;
    int ln = r & 63;
    int lg = ln >> 4, lw = ln & 15;
    int cb = s / 6, k = s - cb * 6;
    int cibase = cb * 64 + (lg + 4 * kk) * 8;
    int col = (k << 8) + mi * 16 + lw;
    bf16_t* dst = wp3 + ((long)idx << 3);
    #pragma unroll
    for (int e = 0; e < 8; ++e)
      dst[e] = (bf16_t)W[(cibase + e) * KD + col];
  } else if (idx < S2) {
    // bias[n][w][c] = sum_k b[k*256+c] * S[n,k,w],  S = col-sum of M (lam folded)
    int j = idx - S1;
    int c = j & 255;
    int nw = j >> 8;
    int w = nw % VV;
    int n = nw / VV;
    float lam = lam_p[0];
    float s = 0.f;
    for (int k = 0; k < KNUM; ++k) {
      float sk = 0.f;
      if (k < ET) {
        for (int v = 0; v < VV; ++v) sk += A[(k * VV + v) * VV + w];
      } else {
        for (int v = 0; v < VV; ++v) sk += Bm[(((n * ET) + (k - ET)) * VV + v) * VV + w];
        sk *= lam;
      }
      s += bvec[(k << 8) + c] * sk;
    }
    biasmat[j] = s;
  } else if (idx < S3) {
    int j = idx - S2;
    outA[j] = A[j];   // second tuple output: A passthrough
  }
}

// ---------------- fused kernel, register-chained MFMA#1 -> MFMA#2 ------------
// Per step (cb,k), per wave: 16x MFMA#1 (Xs x Ms) whose D-fragments, after
// in-lane f32->bf16 packing, ARE the 16x16x32 B-operand fragments for MFMA#2
// (Xs rows stored in interleaved-quad permutation so D rows = lg*8+e order).
// No Bs LDS, no per-step barriers (only Xs restage barriers, 2 per cb).
__global__ __launch_bounds__(512, 2) void fused_kernel(
    const float* __restrict__ x, const float* __restrict__ A,
    const float* __restrict__ Bm, const float* __restrict__ lam_p,
    const bf16_t* __restrict__ wp3, const float* __restrict__ biasmat,
    float* __restrict__ out)
{
  __shared__ bf16_t Xs[256 * 32];        // 16 KB [row'][v] swizzled, permuted rows
  __shared__ bf16_t Ms[KNUM * 32 * 32];  // 12 KB [k][w][v] swizzled, zero-pad

  const int b = blockIdx.x;
  const int n = b >> 4;                  // 0..31
  const int t0 = (b & 15) << 2;          // t-group of 4
  const int tid = threadIdx.x;
  const int wv = tid >> 6, ln = tid & 63;
  const int lw = ln & 15, lg = ln >> 4;
  const float lam = lam_p[0];

  // stage Ms once: row R=k*32+w (64B), group-XOR sw2=(w&3)^((w>>2)&3)
  for (int i = tid; i < KNUM * 32 * 32; i += 512) {
    int R = i >> 5, v = i & 31;
    int k = i >> 10, w = (i >> 5) & 31;
    float val = 0.f;
    if (w < VV && v < VV)
      val = (k < ET) ? A[(k * VV + v) * VV + w]
                     : lam * Bm[(((n * ET) + (k - ET)) * VV + v) * VV + w];
    int sw2 = (w & 3) ^ ((w >> 2) & 3);
    int byteoff = R * 64 + ((((v >> 3) ^ sw2) & 3) << 4) + ((v & 7) << 1);
    *(bf16_t*)((char*)Ms + byteoff) = (bf16_t)val;
  }

  f32x4 acc[4][4] = {};
  const int m_base = (wv >> 1) * 64;
  const int mb4 = (wv >> 1) * 4;         // mi base for A-fragments
  const int n_base = (wv & 1) * 64;
  const int dtb = (wv & 1) * 2;          // this wave's dt base (cols n_base..+63)
  const f32x4 z4 = {0.f, 0.f, 0.f, 0.f};
  const int msw2 = (lw & 3) ^ ((lw >> 2) & 3);   // Ms read swizzle

  for (int cb = 0; cb < 4; ++cb) {
    __syncthreads();   // all waves done reading previous cb's Xs
    // stage Xs, rows permuted: ci -> row' = dt*64 + kk*32 + hi*16 + q*4 + (r&3)
    // (kk=ci>>5, q=(ci>>3)&3, r=ci&7, hi=r>>2) so step reads are linear rows.
    if (tid < 256) {
      int ci = tid >> 2, dt = tid & 3;
      const float* xp = x + ((long)(n * CIN + cb * 64 + ci) * TDIM + t0 + dt) * VV;
      float xv[25];
      #pragma unroll
      for (int v = 0; v < VV; ++v) xv[v] = xp[v];
      int kk = ci >> 5, rem = ci & 31, q = rem >> 3, r = rem & 7;
      int row = dt * 64 + kk * 32 + (r >> 2) * 16 + q * 4 + (r & 3);
      int sw = (row & 3) ^ ((row >> 2) & 3);
      #pragma unroll
      for (int g = 0; g < 4; ++g) {
        char* base = (char*)Xs + row * 64 + ((g ^ sw) & 3) * 16;
        #pragma unroll
        for (int p = 0; p < 4; ++p) {
          int v0 = g * 8 + p * 2;
          float lo = (v0     < VV) ? xv[v0 < VV ? v0 : 0]     : 0.f;
          float hi = (v0 + 1 < VV) ? xv[v0 + 1 < VV ? v0 + 1 : 0] : 0.f;
          *(unsigned*)(base + p * 4) = packbf(lo, hi);
        }
      }
    }
    __syncthreads();   // Xs visible

    #pragma unroll 1
    for (int k = 0; k < KNUM; ++k) {
      const int s = cb * 6 + k;
      // Ms fragments for this k (rows lw, lw+16 within k's 32-w block)
      bf16x8 mb0 = *(const bf16x8*)((const char*)Ms + (k * 32 + lw) * 64 + (((lg ^ msw2) & 3) << 4));
      bf16x8 mb1 = *(const bf16x8*)((const char*)Ms + (k * 32 + 16 + lw) * 64 + (((lg ^ msw2) & 3) << 4));
      const bf16_t* wpS = wp3 + (((long)s * 2048 + (long)mb4 * 128 + ln) << 3);

      #pragma unroll
      for (int kk = 0; kk < 2; ++kk) {
        // A-fragments for MFMA#2 (global, frag-order, L2-hot; R7 layout)
        bf16x8 af2[4];
        #pragma unroll
        for (int i = 0; i < 4; ++i)
          af2[i] = *(const bf16x8*)(wpS + ((i * 128 + kk * 64) << 3));

        // MFMA#1: build the 4 B-fragments (col-tiles) for this kk in-register
        bf16x8 bfrag[4];
        #pragma unroll
        for (int dtl = 0; dtl < 2; ++dtl) {
          int ra = (dtb + dtl) * 64 + kk * 32 + lw;   // linear 16-row tile (a)
          int swa = (ra & 3) ^ ((ra >> 2) & 3);
          int off = ((lg ^ swa) & 3) << 4;
          bf16x8 afa = *(const bf16x8*)((const char*)Xs + ra * 64 + off);
          bf16x8 afb = *(const bf16x8*)((const char*)Xs + (ra + 16) * 64 + off);
          f32x4 da0 = __builtin_amdgcn_mfma_f32_16x16x32_bf16(afa, mb0, z4, 0, 0, 0);
          f32x4 db0 = __builtin_amdgcn_mfma_f32_16x16x32_bf16(afb, mb0, z4, 0, 0, 0);
          f32x4 da1 = __builtin_amdgcn_mfma_f32_16x16x32_bf16(afa, mb1, z4, 0, 0, 0);
          f32x4 db1 = __builtin_amdgcn_mfma_f32_16x16x32_bf16(afb, mb1, z4, 0, 0, 0);
          bfrag[dtl * 2 + 0] = pack8(da0, db0);
          bfrag[dtl * 2 + 1] = pack8(da1, db1);
        }

        // MFMA#2: acc += af2 x bfrag (register-chained, no LDS)
        __builtin_amdgcn_s_setprio(1);
        #pragma unroll
        for (int i = 0; i < 4; ++i)
          #pragma unroll
          for (int j = 0; j < 4; ++j)
            acc[i][j] = __builtin_amdgcn_mfma_f32_16x16x32_bf16(af2[i], bfrag[j], acc[i][j], 0, 0, 0);
        __builtin_amdgcn_s_setprio(0);
      }
    }
  }

  // epilogue: C/D map col=lane&15, row=(lane>>4)*4+reg [m89-verified]
  #pragma unroll
  for (int j = 0; j < 4; ++j) {
    int colb = n_base + j * 16 + lw;         // 0..127
    int dt = colb >> 5, w = colb & 31;
    if (w < VV) {
      float* ob = out + (long)n * 409600 + (t0 + dt) * 25 + w;
      const float* brow = biasmat + (n * 25 + w) * 256;
      #pragma unroll
      for (int i = 0; i < 4; ++i) {
        int mb = m_base + i * 16 + (lg << 2);
        #pragma unroll
        for (int r = 0; r < 4; ++r) {
          int m = mb + r;
          ob[(long)m * 1600] = acc[i][j][r] + brow[m];
        }
      }
    }
  }
}

// ---------------- ws-free fp32 fallback (insurance) ----------------
__global__ __launch_bounds__(256) void fallback_kernel(
    const float* __restrict__ x, const float* __restrict__ A,
    const float* __restrict__ Bm, const float* __restrict__ lam_p,
    const float* __restrict__ W, const float* __restrict__ bvec,
    float* __restrict__ out)
{
  __shared__ __align__(16) float xs[CIN][28];
  __shared__ __align__(16) float Ms[KNUM][VV][28];   // [k][v][w] padded
  const int nt = blockIdx.x;
  const int n = nt >> 6, t = nt & 63;
  const int tid = threadIdx.x;
  const float lam = lam_p[0];

  const float* xp = x + (((long)(n * CIN + tid) * TDIM + t) * VV);
  #pragma unroll
  for (int v = 0; v < VV; ++v) xs[tid][v] = xp[v];
  xs[tid][25] = xs[tid][26] = xs[tid][27] = 0.f;
  for (int i = tid; i < KNUM * VV * VV; i += 256) {
    int k = i / (VV * VV);
    int r = i - k * VV * VV;
    int v = r / VV;
    int w = r - v * VV;
    Ms[k][v][w] = (k < ET) ? A[(k * VV + v) * VV + w]
                           : lam * Bm[(((n * ET) + (k - ET)) * VV + v) * VV + w];
    if (w == 24) { Ms[k][v][25] = Ms[k][v][26] = Ms[k][v][27] = 0.f; }
  }
  __syncthreads();

  float oacc[28] = {};
  for (int k = 0; k < KNUM; ++k) {
    float yv[28];
    float bv = bvec[(k << 8) + tid];
    #pragma unroll
    for (int v = 0; v < 28; ++v) yv[v] = 0.f;
    for (int ci = 0; ci < CIN; ++ci) {
      float wl = W[ci * KD + (k << 8) + tid];
      const f32x4* x4 = (const f32x4*)&xs[ci][0];
      #pragma unroll
      for (int q = 0; q < 7; ++q) {
        f32x4 xv = x4[q];
        yv[q*4+0] += wl*xv[0]; yv[q*4+1] += wl*xv[1];
        yv[q*4+2] += wl*xv[2]; yv[q*4+3] += wl*xv[3];
      }
    }
    #pragma unroll
    for (int v = 0; v < VV; ++v) {
      float yvv = yv[v] + bv;
      const f32x4* m4 = (const f32x4*)&Ms[k][v][0];
      #pragma unroll
      for (int q = 0; q < 7; ++q) {
        f32x4 mv = m4[q];
        oacc[q*4+0] += yvv*mv[0]; oacc[q*4+1] += yvv*mv[1];
        oacc[q*4+2] += yvv*mv[2]; oacc[q*4+3] += yvv*mv[3];
      }
    }
  }
  float* op = out + (((long)(n * COUT + tid) * TDIM + t) * VV);
  #pragma unroll
  for (int w = 0; w < VV; ++w) op[w] = oacc[w];
}

__global__ void copyA_kernel(const float* __restrict__ A, float* __restrict__ outA) {
  int i = blockIdx.x * 256 + threadIdx.x;
  if (i < ACNT) outA[i] = A[i];
}

extern "C" void kernel_launch(void* const* d_in, const int* in_sizes, int n_in,
                              void* d_out, int out_size, void* d_ws, size_t ws_size,
                              hipStream_t stream) {
  const float* x   = (const float*)d_in[0];
  const float* A   = (const float*)d_in[1];
  const float* Bm  = (const float*)d_in[2];
  const float* lam = (const float*)d_in[3];
  const float* W   = (const float*)d_in[4];
  const float* bv  = (const float*)d_in[5];
  float* out = (float*)d_out;

  if (d_ws != nullptr && ws_size >= WS_NEED) {
    bf16_t* wp3     = (bf16_t*)d_ws;
    float*  biasmat = (float*)((char*)d_ws + BIAS_OFF);
    constexpr int PREP_ITEMS = WP3_CHUNKS + NB * VV * COUT + ACNT;
    prep_kernel<<<(PREP_ITEMS + 255) / 256, 256, 0, stream>>>(A, Bm, lam, W, bv, wp3, biasmat, out + OUT0);
    fused_kernel<<<NB * 16, 512, 0, stream>>>(x, A, Bm, lam, wp3, biasmat, out);
  } else {
    fallback_kernel<<<NB * TDIM, 256, 0, stream>>>(x, A, Bm, lam, W, bv, out);
    copyA_kernel<<<(ACNT + 255) / 256, 256, 0, stream>>>(A, out + OUT0);
  }
}